// Round 3
// baseline (1051.719 us; speedup 1.0000x reference)
//
#include <hip/hip_runtime.h>
#include <hip/hip_bf16.h>

#define N_NODES 65536
#define N_EDGES 1048576
#define IN_DIM 96
#define HID 128
#define OUTD 256
#define N_ACT 20
#define NPB_MLP 8    // nodes per block, k_mlp (128 thr)
#define NPB_PROJ 16  // nodes per block, k_proj (256 thr)

typedef unsigned short u16;
typedef unsigned int u32;

// intermediates stored as bf16 to halve gather traffic; all math in fp32
__device__ __forceinline__ float bf2f(u16 v) { return __uint_as_float(((u32)v) << 16); }
__device__ __forceinline__ u16 f2bf(float f) {
    u32 x = __float_as_uint(f);
    return (u16)((x + 0x7fffu + ((x >> 16) & 1u)) >> 16);
}

__device__ __forceinline__ float wsum(float v) {
#pragma unroll
    for (int o = 32; o > 0; o >>= 1) v += __shfl_xor(v, o, 64);
    return v;
}
__device__ __forceinline__ float wmax(float v) {
#pragma unroll
    for (int o = 32; o > 0; o >>= 1) v = fmaxf(v, __shfl_xor(v, o, 64));
    return v;
}

// block of 128 threads (2 waves): reduce (s, q) across block
__device__ __forceinline__ void block_reduce2_128(float& s, float& q, float* red) {
#pragma unroll
    for (int o = 32; o > 0; o >>= 1) { s += __shfl_xor(s, o, 64); q += __shfl_xor(q, o, 64); }
    int tid = threadIdx.x;
    __syncthreads();
    if ((tid & 63) == 0) { red[(tid >> 6) * 2] = s; red[(tid >> 6) * 2 + 1] = q; }
    __syncthreads();
    s = red[0] + red[2];
    q = red[1] + red[3];
}

// ---------------- zero deg+cursor ----------------
__global__ __launch_bounds__(256) void k_zero(int* __restrict__ p) {
    p[blockIdx.x * 256 + threadIdx.x] = 0;
}

// ---------------- degree count ----------------
__global__ __launch_bounds__(256) void k_deg(const int* __restrict__ ei, int* __restrict__ deg) {
    int e = blockIdx.x * 256 + threadIdx.x;
    atomicAdd(deg + ei[N_EDGES + e], 1);
}

// ---------------- exclusive scan of degrees -> CSR offsets ----------------
__global__ __launch_bounds__(1024) void k_scan(const int* __restrict__ deg, int* __restrict__ off) {
    __shared__ int part[1024];
    int t = threadIdx.x;
    int base = t * 64;
    int s = 0;
    for (int i = 0; i < 64; i++) s += deg[base + i];
    part[t] = s;
    __syncthreads();
    for (int o = 1; o < 1024; o <<= 1) {
        int v = (t >= o) ? part[t - o] : 0;
        __syncthreads();
        part[t] += v;
        __syncthreads();
    }
    int run = (t == 0) ? 0 : part[t - 1];
    for (int i = 0; i < 64; i++) {
        off[base + i] = run;
        run += deg[base + i];
    }
    if (t == 1023) off[N_NODES] = run;
}

// ---------------- MLP (96 -> 128 -> 128, relu+LN each), fp32 in, bf16 out ----------------
__global__ __launch_bounds__(128) void k_mlp(
    const float* __restrict__ in,
    const float* __restrict__ W0, const float* __restrict__ b0,
    const float* __restrict__ g0, const float* __restrict__ be0,
    const float* __restrict__ W1, const float* __restrict__ b1,
    const float* __restrict__ g1, const float* __restrict__ be1,
    u16* __restrict__ x1out)
{
    int tid = threadIdx.x;
    int n0 = blockIdx.x * NPB_MLP;
    __shared__ float xin[NPB_MLP][IN_DIM];
    __shared__ float x0[NPB_MLP][HID];
    __shared__ float red[4];

    for (int i = tid; i < NPB_MLP * IN_DIM; i += 128)
        ((float*)xin)[i] = in[(long)n0 * IN_DIM + i];
    __syncthreads();

    float acc[NPB_MLP];
    // layer 0
    {
        float bb = b0[tid];
#pragma unroll
        for (int i = 0; i < NPB_MLP; i++) acc[i] = bb;
        for (int k = 0; k < IN_DIM; k++) {
            float w = W0[k * HID + tid];
#pragma unroll
            for (int i = 0; i < NPB_MLP; i++) acc[i] = fmaf(xin[i][k], w, acc[i]);
        }
        float gv = g0[tid], bev = be0[tid];
        for (int i = 0; i < NPB_MLP; i++) {
            float a = fmaxf(acc[i], 0.f);
            float s = a, q = a * a;
            block_reduce2_128(s, q, red);
            float mu = s * (1.f / HID);
            float var = q * (1.f / HID) - mu * mu;
            float rs = rsqrtf(fmaxf(var, 0.f) + 1e-5f);
            x0[i][tid] = (a - mu) * rs * gv + bev;
        }
    }
    __syncthreads();

    // layer 1
    {
        float bb = b1[tid];
#pragma unroll
        for (int i = 0; i < NPB_MLP; i++) acc[i] = bb;
        for (int k = 0; k < HID; k++) {
            float w = W1[k * HID + tid];
#pragma unroll
            for (int i = 0; i < NPB_MLP; i++) acc[i] = fmaf(x0[i][k], w, acc[i]);
        }
        float gv = g1[tid], bev = be1[tid];
        for (int i = 0; i < NPB_MLP; i++) {
            float a = fmaxf(acc[i], 0.f);
            float s = a, q = a * a;
            block_reduce2_128(s, q, red);
            float mu = s * (1.f / HID);
            float var = q * (1.f / HID) - mu * mu;
            float rs = rsqrtf(fmaxf(var, 0.f) + 1e-5f);
            x1out[(long)(n0 + i) * HID + tid] = f2bf((a - mu) * rs * gv + bev);
        }
    }
}

// ---------------- projections xl, xr, residual (all bf16 out), 16 nodes/block ----------------
__global__ __launch_bounds__(256) void k_proj(
    const u16* __restrict__ x1,
    const float* __restrict__ Wl, const float* __restrict__ bl,
    const float* __restrict__ Wr, const float* __restrict__ br,
    const float* __restrict__ Wres, const float* __restrict__ gbias,
    u16* __restrict__ xl, u16* __restrict__ xr, u16* __restrict__ hres)
{
    int j = threadIdx.x;
    int n0 = blockIdx.x * NPB_PROJ;
    __shared__ float x[NPB_PROJ][HID];
    for (int i = j; i < NPB_PROJ * HID; i += 256)
        ((float*)x)[i] = bf2f(x1[(long)n0 * HID + i]);
    __syncthreads();

    float a[NPB_PROJ], b[NPB_PROJ], c[NPB_PROJ];
    float bla = bl[j], bra = br[j], gba = gbias[j];
#pragma unroll
    for (int i = 0; i < NPB_PROJ; i++) { a[i] = bla; b[i] = bra; c[i] = gba; }

    for (int k = 0; k < HID; k++) {
        float wl = Wl[k * OUTD + j];
        float wr = Wr[k * OUTD + j];
        float wq = Wres[k * OUTD + j];
#pragma unroll
        for (int i = 0; i < NPB_PROJ; i++) {
            float xv = x[i][k];
            a[i] = fmaf(xv, wl, a[i]);
            b[i] = fmaf(xv, wr, b[i]);
            c[i] = fmaf(xv, wq, c[i]);
        }
    }
#pragma unroll
    for (int i = 0; i < NPB_PROJ; i++) {
        long row = (long)(n0 + i) * OUTD + j;
        xl[row] = f2bf(a[i]);
        xr[row] = f2bf(b[i]);
        hres[row] = f2bf(c[i]);
    }
}

// ---------------- per-edge attention logit + CSR scatter (1 wave/edge) ----------------
__global__ __launch_bounds__(256) void k_edge_scatter(
    const int* __restrict__ ei, const float* __restrict__ ea,
    const float* __restrict__ We, const float* __restrict__ att,
    const u16* __restrict__ xl, const u16* __restrict__ xr,
    const int* __restrict__ off, int* __restrict__ cursor,
    int* __restrict__ ssrc, float* __restrict__ se)
{
    int wid = threadIdx.x >> 6, lane = threadIdx.x & 63;
    int e = blockIdx.x * 4 + wid;
    int src = ei[e];
    int dst = ei[N_EDGES + e];
    float ea0 = ea[e * 3 + 0];
    float ea1 = ea[e * 3 + 1];
    float ea2 = ea[e * 3 + 2];
    int j0 = lane * 4;

    ushort4 xlv = *(const ushort4*)(xl + (long)src * OUTD + j0);
    ushort4 xrv = *(const ushort4*)(xr + (long)dst * OUTD + j0);
    float4 w0 = *(const float4*)(We + j0);
    float4 w1 = *(const float4*)(We + OUTD + j0);
    float4 w2 = *(const float4*)(We + 2 * OUTD + j0);
    float4 av = *(const float4*)(att + j0);

    float p = 0.f;
    {
        float m = bf2f(xlv.x) + bf2f(xrv.x) + ea0 * w0.x + ea1 * w1.x + ea2 * w2.x;
        m = (m > 0.f) ? m : 0.2f * m;
        p = fmaf(m, av.x, p);
    }
    {
        float m = bf2f(xlv.y) + bf2f(xrv.y) + ea0 * w0.y + ea1 * w1.y + ea2 * w2.y;
        m = (m > 0.f) ? m : 0.2f * m;
        p = fmaf(m, av.y, p);
    }
    {
        float m = bf2f(xlv.z) + bf2f(xrv.z) + ea0 * w0.z + ea1 * w1.z + ea2 * w2.z;
        m = (m > 0.f) ? m : 0.2f * m;
        p = fmaf(m, av.z, p);
    }
    {
        float m = bf2f(xlv.w) + bf2f(xrv.w) + ea0 * w0.w + ea1 * w1.w + ea2 * w2.w;
        m = (m > 0.f) ? m : 0.2f * m;
        p = fmaf(m, av.w, p);
    }
    p = wsum(p);
    if (lane == 0) {
        int pos = off[dst] + atomicAdd(cursor + dst, 1);
        ssrc[pos] = src;
        se[pos] = p;
    }
}

// ---------------- per-node softmax + aggregate + residual + relu/LN + head ----------------
__global__ __launch_bounds__(256) void k_agg(
    const int* __restrict__ off, const int* __restrict__ ssrc, const float* __restrict__ se,
    const u16* __restrict__ xl, const u16* __restrict__ hres,
    const float* __restrict__ g2, const float* __restrict__ be2,
    const float* __restrict__ Wq, const float* __restrict__ bq,
    float* __restrict__ out)
{
    int wid = threadIdx.x >> 6, lane = threadIdx.x & 63;
    int n = blockIdx.x * 4 + wid;
    __shared__ float lds[4][OUTD + 4];

    int beg = off[n], end = off[n + 1];
    int deg = end - beg;

    float m = -3.4e38f;
    for (int i = lane; i < deg; i += 64) m = fmaxf(m, se[beg + i]);
    m = wmax(m);
    float s = 0.f;
    for (int i = lane; i < deg; i += 64) s += expf(se[beg + i] - m);
    s = wsum(s);
    float inv = (deg > 0) ? 1.f / s : 0.f;

    int j0 = lane * 4;
    float acc0 = 0.f, acc1 = 0.f, acc2 = 0.f, acc3 = 0.f;
    for (int i = 0; i < deg; i++) {
        int sn = ssrc[beg + i];
        float al = expf(se[beg + i] - m) * inv;
        ushort4 v = *(const ushort4*)(xl + (long)sn * OUTD + j0);
        acc0 = fmaf(al, bf2f(v.x), acc0);
        acc1 = fmaf(al, bf2f(v.y), acc1);
        acc2 = fmaf(al, bf2f(v.z), acc2);
        acc3 = fmaf(al, bf2f(v.w), acc3);
    }

    ushort4 hv = *(const ushort4*)(hres + (long)n * OUTD + j0);
    float h0 = fmaxf(acc0 + bf2f(hv.x), 0.f);
    float h1 = fmaxf(acc1 + bf2f(hv.y), 0.f);
    float h2 = fmaxf(acc2 + bf2f(hv.z), 0.f);
    float h3 = fmaxf(acc3 + bf2f(hv.w), 0.f);

    float sum = h0 + h1 + h2 + h3;
    float sq = h0 * h0 + h1 * h1 + h2 * h2 + h3 * h3;
    sum = wsum(sum);
    sq = wsum(sq);
    float mu = sum * (1.f / OUTD);
    float var = sq * (1.f / OUTD) - mu * mu;
    float rs = rsqrtf(fmaxf(var, 0.f) + 1e-5f);

    float4 gv = *(const float4*)(g2 + j0);
    float4 bv = *(const float4*)(be2 + j0);
    lds[wid][j0 + 0] = (h0 - mu) * rs * gv.x + bv.x;
    lds[wid][j0 + 1] = (h1 - mu) * rs * gv.y + bv.y;
    lds[wid][j0 + 2] = (h2 - mu) * rs * gv.z + bv.z;
    lds[wid][j0 + 3] = (h3 - mu) * rs * gv.w + bv.w;
    __syncthreads();

    if (lane < N_ACT) {
        float qv = bq[lane];
#pragma unroll 4
        for (int j = 0; j < OUTD; j++) qv = fmaf(lds[wid][j], Wq[j * N_ACT + lane], qv);
        out[(long)n * N_ACT + lane] = qv;
    }
}

extern "C" void kernel_launch(void* const* d_in, const int* in_sizes, int n_in,
                              void* d_out, int out_size, void* d_ws, size_t ws_size,
                              hipStream_t stream) {
    (void)in_sizes; (void)n_in; (void)out_size; (void)ws_size;
    const float* inp  = (const float*)d_in[0];
    const int*   ei   = (const int*)d_in[1];
    const float* ea   = (const float*)d_in[2];
    const float* W0   = (const float*)d_in[3];
    const float* b0   = (const float*)d_in[4];
    const float* g0   = (const float*)d_in[5];
    const float* be0  = (const float*)d_in[6];
    const float* W1   = (const float*)d_in[7];
    const float* b1   = (const float*)d_in[8];
    const float* g1   = (const float*)d_in[9];
    const float* be1  = (const float*)d_in[10];
    const float* Wl   = (const float*)d_in[11];
    const float* bl   = (const float*)d_in[12];
    const float* Wr   = (const float*)d_in[13];
    const float* br   = (const float*)d_in[14];
    const float* We   = (const float*)d_in[15];
    const float* att  = (const float*)d_in[16];
    const float* Wres = (const float*)d_in[17];
    const float* gbias= (const float*)d_in[18];
    const float* g2   = (const float*)d_in[19];
    const float* be2  = (const float*)d_in[20];
    const float* Wq   = (const float*)d_in[21];
    const float* bq   = (const float*)d_in[22];
    float* out = (float*)d_out;

    char* ws = (char*)d_ws;
    size_t o = 0;
    auto alloc = [&](size_t bytes) -> void* {
        void* p = ws + o;
        o += (bytes + 255) & ~(size_t)255;
        return p;
    };
    // total ~121 MiB
    u16*   x1     = (u16*)  alloc((size_t)N_NODES * HID * 2);     // 16 MiB
    u16*   xl     = (u16*)  alloc((size_t)N_NODES * OUTD * 2);    // 32 MiB
    u16*   xr     = (u16*)  alloc((size_t)N_NODES * OUTD * 2);    // 32 MiB
    u16*   hres   = (u16*)  alloc((size_t)N_NODES * OUTD * 2);    // 32 MiB
    int*   deg    = (int*)  alloc((size_t)N_NODES * 4);           // 256 KiB
    int*   cursor = (int*)  alloc((size_t)N_NODES * 4);           // 256 KiB (contiguous with deg)
    int*   off    = (int*)  alloc((size_t)(N_NODES + 1) * 4);
    int*   ssrc   = (int*)  alloc((size_t)N_EDGES * 4);           // 4 MiB
    float* se     = (float*)alloc((size_t)N_EDGES * 4);           // 4 MiB

    k_zero<<<(2 * N_NODES) / 256, 256, 0, stream>>>(deg);  // zeroes deg + cursor
    k_deg<<<N_EDGES / 256, 256, 0, stream>>>(ei, deg);
    k_scan<<<1, 1024, 0, stream>>>(deg, off);
    k_mlp<<<N_NODES / NPB_MLP, 128, 0, stream>>>(inp, W0, b0, g0, be0, W1, b1, g1, be1, x1);
    k_proj<<<N_NODES / NPB_PROJ, 256, 0, stream>>>(x1, Wl, bl, Wr, br, Wres, gbias, xl, xr, hres);
    k_edge_scatter<<<N_EDGES / 4, 256, 0, stream>>>(ei, ea, We, att, xl, xr, off, cursor, ssrc, se);
    k_agg<<<N_NODES / 4, 256, 0, stream>>>(off, ssrc, se, xl, hres, g2, be2, Wq, bq, out);
}

// Round 4
// 867.265 us; speedup vs baseline: 1.2127x; 1.2127x over previous
//
#include <hip/hip_runtime.h>
#include <hip/hip_bf16.h>

#define N_NODES 65536
#define N_EDGES 1048576
#define IN_DIM 96
#define HID 128
#define OUTD 256
#define N_ACT 20
#define NPB_MLP 8    // nodes per block, k_mlp (128 thr)
#define NPB_PROJ 16  // nodes per block, k_proj (256 thr)

typedef unsigned short u16;
typedef unsigned int u32;

// intermediates stored as bf16 to halve gather traffic; all math in fp32
__device__ __forceinline__ float bf2f(u16 v) { return __uint_as_float(((u32)v) << 16); }
__device__ __forceinline__ u16 f2bf(float f) {
    u32 x = __float_as_uint(f);
    return (u16)((x + 0x7fffu + ((x >> 16) & 1u)) >> 16);
}

__device__ __forceinline__ float wsum(float v) {
#pragma unroll
    for (int o = 32; o > 0; o >>= 1) v += __shfl_xor(v, o, 64);
    return v;
}

// block of 128 threads (2 waves): reduce (s, q) across block
__device__ __forceinline__ void block_reduce2_128(float& s, float& q, float* red) {
#pragma unroll
    for (int o = 32; o > 0; o >>= 1) { s += __shfl_xor(s, o, 64); q += __shfl_xor(q, o, 64); }
    int tid = threadIdx.x;
    __syncthreads();
    if ((tid & 63) == 0) { red[(tid >> 6) * 2] = s; red[(tid >> 6) * 2 + 1] = q; }
    __syncthreads();
    s = red[0] + red[2];
    q = red[1] + red[3];
}

// ---------------- zero deg+cursor ----------------
__global__ __launch_bounds__(256) void k_zero(int* __restrict__ p) {
    p[blockIdx.x * 256 + threadIdx.x] = 0;
}

// ---------------- degree count ----------------
__global__ __launch_bounds__(256) void k_deg(const int* __restrict__ ei, int* __restrict__ deg) {
    int e = blockIdx.x * 256 + threadIdx.x;
    atomicAdd(deg + ei[N_EDGES + e], 1);
}

// ---------------- exclusive scan of degrees -> CSR offsets ----------------
__global__ __launch_bounds__(1024) void k_scan(const int* __restrict__ deg, int* __restrict__ off) {
    __shared__ int part[1024];
    int t = threadIdx.x;
    int base = t * 64;
    int s = 0;
    for (int i = 0; i < 64; i++) s += deg[base + i];
    part[t] = s;
    __syncthreads();
    for (int o = 1; o < 1024; o <<= 1) {
        int v = (t >= o) ? part[t - o] : 0;
        __syncthreads();
        part[t] += v;
        __syncthreads();
    }
    int run = (t == 0) ? 0 : part[t - 1];
    for (int i = 0; i < 64; i++) {
        off[base + i] = run;
        run += deg[base + i];
    }
    if (t == 1023) off[N_NODES] = run;
}

// ---------------- scatter edge records (src + 3 attrs) into CSR order ----------------
__global__ __launch_bounds__(256) void k_scatter(
    const int* __restrict__ ei, const float* __restrict__ ea,
    const int* __restrict__ off, int* __restrict__ cursor,
    int4* __restrict__ erec)
{
    int e = blockIdx.x * 256 + threadIdx.x;
    int src = ei[e];
    int dst = ei[N_EDGES + e];
    float a0 = ea[e * 3 + 0];
    float a1 = ea[e * 3 + 1];
    float a2 = ea[e * 3 + 2];
    int pos = off[dst] + atomicAdd(cursor + dst, 1);
    erec[pos] = make_int4(src, __float_as_int(a0), __float_as_int(a1), __float_as_int(a2));
}

// ---------------- MLP (96 -> 128 -> 128, relu+LN each), fp32 in, bf16 out ----------------
__global__ __launch_bounds__(128) void k_mlp(
    const float* __restrict__ in,
    const float* __restrict__ W0, const float* __restrict__ b0,
    const float* __restrict__ g0, const float* __restrict__ be0,
    const float* __restrict__ W1, const float* __restrict__ b1,
    const float* __restrict__ g1, const float* __restrict__ be1,
    u16* __restrict__ x1out)
{
    int tid = threadIdx.x;
    int n0 = blockIdx.x * NPB_MLP;
    __shared__ float xin[NPB_MLP][IN_DIM];
    __shared__ float x0[NPB_MLP][HID];
    __shared__ float red[4];

    for (int i = tid; i < NPB_MLP * IN_DIM; i += 128)
        ((float*)xin)[i] = in[(long)n0 * IN_DIM + i];
    __syncthreads();

    float acc[NPB_MLP];
    // layer 0
    {
        float bb = b0[tid];
#pragma unroll
        for (int i = 0; i < NPB_MLP; i++) acc[i] = bb;
        for (int k = 0; k < IN_DIM; k++) {
            float w = W0[k * HID + tid];
#pragma unroll
            for (int i = 0; i < NPB_MLP; i++) acc[i] = fmaf(xin[i][k], w, acc[i]);
        }
        float gv = g0[tid], bev = be0[tid];
        for (int i = 0; i < NPB_MLP; i++) {
            float a = fmaxf(acc[i], 0.f);
            float s = a, q = a * a;
            block_reduce2_128(s, q, red);
            float mu = s * (1.f / HID);
            float var = q * (1.f / HID) - mu * mu;
            float rs = rsqrtf(fmaxf(var, 0.f) + 1e-5f);
            x0[i][tid] = (a - mu) * rs * gv + bev;
        }
    }
    __syncthreads();

    // layer 1
    {
        float bb = b1[tid];
#pragma unroll
        for (int i = 0; i < NPB_MLP; i++) acc[i] = bb;
        for (int k = 0; k < HID; k++) {
            float w = W1[k * HID + tid];
#pragma unroll
            for (int i = 0; i < NPB_MLP; i++) acc[i] = fmaf(x0[i][k], w, acc[i]);
        }
        float gv = g1[tid], bev = be1[tid];
        for (int i = 0; i < NPB_MLP; i++) {
            float a = fmaxf(acc[i], 0.f);
            float s = a, q = a * a;
            block_reduce2_128(s, q, red);
            float mu = s * (1.f / HID);
            float var = q * (1.f / HID) - mu * mu;
            float rs = rsqrtf(fmaxf(var, 0.f) + 1e-5f);
            x1out[(long)(n0 + i) * HID + tid] = f2bf((a - mu) * rs * gv + bev);
        }
    }
}

// ---------------- projections xl, xr, residual (all bf16 out), 16 nodes/block ----------------
__global__ __launch_bounds__(256) void k_proj(
    const u16* __restrict__ x1,
    const float* __restrict__ Wl, const float* __restrict__ bl,
    const float* __restrict__ Wr, const float* __restrict__ br,
    const float* __restrict__ Wres, const float* __restrict__ gbias,
    u16* __restrict__ xl, u16* __restrict__ xr, u16* __restrict__ hres)
{
    int j = threadIdx.x;
    int n0 = blockIdx.x * NPB_PROJ;
    __shared__ float x[NPB_PROJ][HID];
    for (int i = j; i < NPB_PROJ * HID; i += 256)
        ((float*)x)[i] = bf2f(x1[(long)n0 * HID + i]);
    __syncthreads();

    float a[NPB_PROJ], b[NPB_PROJ], c[NPB_PROJ];
    float bla = bl[j], bra = br[j], gba = gbias[j];
#pragma unroll
    for (int i = 0; i < NPB_PROJ; i++) { a[i] = bla; b[i] = bra; c[i] = gba; }

    for (int k = 0; k < HID; k++) {
        float wl = Wl[k * OUTD + j];
        float wr = Wr[k * OUTD + j];
        float wq = Wres[k * OUTD + j];
#pragma unroll
        for (int i = 0; i < NPB_PROJ; i++) {
            float xv = x[i][k];
            a[i] = fmaf(xv, wl, a[i]);
            b[i] = fmaf(xv, wr, b[i]);
            c[i] = fmaf(xv, wq, c[i]);
        }
    }
#pragma unroll
    for (int i = 0; i < NPB_PROJ; i++) {
        long row = (long)(n0 + i) * OUTD + j;
        xl[row] = f2bf(a[i]);
        xr[row] = f2bf(b[i]);
        hres[row] = f2bf(c[i]);
    }
}

// ---------------- fused: per-edge score + online softmax + aggregate + residual + relu/LN + head ----------------
// 1 wave per node; lanes cover 256 dims (4 each). Single xl[src] gather per edge.
__global__ __launch_bounds__(256) void k_agg_fused(
    const int* __restrict__ off, const int4* __restrict__ erec,
    const u16* __restrict__ xl, const u16* __restrict__ xr, const u16* __restrict__ hres,
    const float* __restrict__ We, const float* __restrict__ att,
    const float* __restrict__ g2, const float* __restrict__ be2,
    const float* __restrict__ Wq, const float* __restrict__ bq,
    float* __restrict__ out)
{
    int wid = threadIdx.x >> 6, lane = threadIdx.x & 63;
    int n = blockIdx.x * 4 + wid;
    int j0 = lane * 4;
    __shared__ float lds[4][OUTD + 4];

    // per-lane constants (L1/L2-resident broadcast reads)
    float4 w0 = *(const float4*)(We + j0);
    float4 w1 = *(const float4*)(We + OUTD + j0);
    float4 w2 = *(const float4*)(We + 2 * OUTD + j0);
    float4 av = *(const float4*)(att + j0);

    ushort4 xrv = *(const ushort4*)(xr + (long)n * OUTD + j0);
    float xr0 = bf2f(xrv.x), xr1 = bf2f(xrv.y), xr2 = bf2f(xrv.z), xr3 = bf2f(xrv.w);

    int beg = off[n], end = off[n + 1];

    float m = -3.0e38f, s = 0.f;
    float a0 = 0.f, a1 = 0.f, a2 = 0.f, a3 = 0.f;

    int4 rec;
    if (beg < end) rec = erec[beg];
    for (int i = beg; i < end; i++) {
        int4 nrec;
        if (i + 1 < end) nrec = erec[i + 1];   // prefetch next edge record
        int src = rec.x;
        float ea0 = __int_as_float(rec.y);
        float ea1 = __int_as_float(rec.z);
        float ea2 = __int_as_float(rec.w);

        ushort4 v = *(const ushort4*)(xl + (long)src * OUTD + j0);
        float x0 = bf2f(v.x), x1v = bf2f(v.y), x2 = bf2f(v.z), x3 = bf2f(v.w);

        float m0 = x0 + xr0 + ea0 * w0.x + ea1 * w1.x + ea2 * w2.x;
        float m1 = x1v + xr1 + ea0 * w0.y + ea1 * w1.y + ea2 * w2.y;
        float m2 = x2 + xr2 + ea0 * w0.z + ea1 * w1.z + ea2 * w2.z;
        float m3 = x3 + xr3 + ea0 * w0.w + ea1 * w1.w + ea2 * w2.w;
        // leakyrelu(x, 0.2) == max(x, 0.2x) for slope < 1
        float p = fmaxf(m0, 0.2f * m0) * av.x;
        p = fmaf(fmaxf(m1, 0.2f * m1), av.y, p);
        p = fmaf(fmaxf(m2, 0.2f * m2), av.z, p);
        p = fmaf(fmaxf(m3, 0.2f * m3), av.w, p);
        p = wsum(p);

        // online softmax update (branchless rescale)
        float mn = fmaxf(m, p);
        float fac = __expf(m - mn);      // first iter: exp(-3e38 - p) -> 0, finite
        float w = __expf(p - mn);
        s = fmaf(s, fac, w);
        a0 = fmaf(a0, fac, w * x0);
        a1 = fmaf(a1, fac, w * x1v);
        a2 = fmaf(a2, fac, w * x2);
        a3 = fmaf(a3, fac, w * x3);
        m = mn;
        rec = nrec;
    }

    float inv = (end > beg) ? 1.f / s : 0.f;

    ushort4 hv = *(const ushort4*)(hres + (long)n * OUTD + j0);
    float h0 = fmaxf(fmaf(a0, inv, bf2f(hv.x)), 0.f);
    float h1 = fmaxf(fmaf(a1, inv, bf2f(hv.y)), 0.f);
    float h2 = fmaxf(fmaf(a2, inv, bf2f(hv.z)), 0.f);
    float h3 = fmaxf(fmaf(a3, inv, bf2f(hv.w)), 0.f);

    float sum = h0 + h1 + h2 + h3;
    float sq = h0 * h0 + h1 * h1 + h2 * h2 + h3 * h3;
    sum = wsum(sum);
    sq = wsum(sq);
    float mu = sum * (1.f / OUTD);
    float var = sq * (1.f / OUTD) - mu * mu;
    float rs = rsqrtf(fmaxf(var, 0.f) + 1e-5f);

    float4 gv = *(const float4*)(g2 + j0);
    float4 bv = *(const float4*)(be2 + j0);
    lds[wid][j0 + 0] = (h0 - mu) * rs * gv.x + bv.x;
    lds[wid][j0 + 1] = (h1 - mu) * rs * gv.y + bv.y;
    lds[wid][j0 + 2] = (h2 - mu) * rs * gv.z + bv.z;
    lds[wid][j0 + 3] = (h3 - mu) * rs * gv.w + bv.w;
    __syncthreads();

    if (lane < N_ACT) {
        float qv = bq[lane];
#pragma unroll 4
        for (int j = 0; j < OUTD; j++) qv = fmaf(lds[wid][j], Wq[j * N_ACT + lane], qv);
        out[(long)n * N_ACT + lane] = qv;
    }
}

extern "C" void kernel_launch(void* const* d_in, const int* in_sizes, int n_in,
                              void* d_out, int out_size, void* d_ws, size_t ws_size,
                              hipStream_t stream) {
    (void)in_sizes; (void)n_in; (void)out_size; (void)ws_size;
    const float* inp  = (const float*)d_in[0];
    const int*   ei   = (const int*)d_in[1];
    const float* ea   = (const float*)d_in[2];
    const float* W0   = (const float*)d_in[3];
    const float* b0   = (const float*)d_in[4];
    const float* g0   = (const float*)d_in[5];
    const float* be0  = (const float*)d_in[6];
    const float* W1   = (const float*)d_in[7];
    const float* b1   = (const float*)d_in[8];
    const float* g1   = (const float*)d_in[9];
    const float* be1  = (const float*)d_in[10];
    const float* Wl   = (const float*)d_in[11];
    const float* bl   = (const float*)d_in[12];
    const float* Wr   = (const float*)d_in[13];
    const float* br   = (const float*)d_in[14];
    const float* We   = (const float*)d_in[15];
    const float* att  = (const float*)d_in[16];
    const float* Wres = (const float*)d_in[17];
    const float* gbias= (const float*)d_in[18];
    const float* g2   = (const float*)d_in[19];
    const float* be2  = (const float*)d_in[20];
    const float* Wq   = (const float*)d_in[21];
    const float* bq   = (const float*)d_in[22];
    float* out = (float*)d_out;

    char* ws = (char*)d_ws;
    size_t o = 0;
    auto alloc = [&](size_t bytes) -> void* {
        void* p = ws + o;
        o += (bytes + 255) & ~(size_t)255;
        return p;
    };
    // total ~129 MiB
    u16*   x1     = (u16*)  alloc((size_t)N_NODES * HID * 2);     // 16 MiB
    u16*   xl     = (u16*)  alloc((size_t)N_NODES * OUTD * 2);    // 32 MiB
    u16*   xr     = (u16*)  alloc((size_t)N_NODES * OUTD * 2);    // 32 MiB
    u16*   hres   = (u16*)  alloc((size_t)N_NODES * OUTD * 2);    // 32 MiB
    int*   deg    = (int*)  alloc((size_t)N_NODES * 4);           // 256 KiB
    int*   cursor = (int*)  alloc((size_t)N_NODES * 4);           // 256 KiB (contiguous with deg)
    int*   off    = (int*)  alloc((size_t)(N_NODES + 1) * 4);
    int4*  erec   = (int4*) alloc((size_t)N_EDGES * 16);          // 16 MiB

    k_zero<<<(2 * N_NODES) / 256, 256, 0, stream>>>(deg);  // zeroes deg + cursor
    k_deg<<<N_EDGES / 256, 256, 0, stream>>>(ei, deg);
    k_scan<<<1, 1024, 0, stream>>>(deg, off);
    k_scatter<<<N_EDGES / 256, 256, 0, stream>>>(ei, ea, off, cursor, erec);
    k_mlp<<<N_NODES / NPB_MLP, 128, 0, stream>>>(inp, W0, b0, g0, be0, W1, b1, g1, be1, x1);
    k_proj<<<N_NODES / NPB_PROJ, 256, 0, stream>>>(x1, Wl, bl, Wr, br, Wres, gbias, xl, xr, hres);
    k_agg_fused<<<N_NODES / 4, 256, 0, stream>>>(off, erec, xl, xr, hres, We, att, g2, be2, Wq, bq, out);
}